// Round 7
// baseline (1599.676 us; speedup 1.0000x reference)
//
#include <hip/hip_runtime.h>
#include <stdint.h>

#define NTHR 256
#define PP   32              // patches per block
#define PR   32              // patch row elems (3c * 9x packed into 32)
#define PY   11              // rows incl. zero-pad rows y=0, y=10
#define PATCH_E (PY*PR)      // 352 elems per patch
#define HST  104             // H row stride in bf16 elems (52 u32)
#define WST  104             // W2g row stride in bf16 elems
#define KG   96              // K per group (3 MFMA steps of 32)

typedef __attribute__((ext_vector_type(8))) short bf16x8;
typedef __attribute__((ext_vector_type(4))) float f32x4;
typedef uint32_t u32;
typedef uint16_t u16;

__device__ __forceinline__ u16 f2bf(float f){
    u32 x = __float_as_uint(f);
    return (u16)((x + 0x7fffu + ((x >> 16) & 1u)) >> 16);
}
__device__ __forceinline__ void up2(u32 w, float& lo, float& hi){
    lo = __uint_as_float(w << 16);
    hi = __uint_as_float(w & 0xffff0000u);
}

// ---- conv1, single channel: one task = (patch p, out row yo), 9 outputs ----
__device__ __forceinline__ void conv1_one(const u16* __restrict__ Pf, int p, int yo,
                                          const float* __restrict__ W1c, float bias,
                                          u16* out9)
{
    float a[9];
    #pragma unroll
    for (int x = 0; x < 9; ++x) a[x] = bias;
    const u16* base = Pf + p * PATCH_E + yo * PR;   // padded row index yy+1 = yo+dy
    #pragma unroll
    for (int dy = 0; dy < 3; ++dy){
        const u16* row = base + dy * PR;            // 16B aligned (PR=32, PATCH_E=352)
        uint4 q0 = *(const uint4*)(row);
        uint4 q1 = *(const uint4*)(row + 8);
        uint4 q2 = *(const uint4*)(row + 16);
        uint2 q3 = *(const uint2*)(row + 24);
        float r[27];
        up2(q0.x, r[0],  r[1]);  up2(q0.y, r[2],  r[3]);
        up2(q0.z, r[4],  r[5]);  up2(q0.w, r[6],  r[7]);
        up2(q1.x, r[8],  r[9]);  up2(q1.y, r[10], r[11]);
        up2(q1.z, r[12], r[13]); up2(q1.w, r[14], r[15]);
        up2(q2.x, r[16], r[17]); up2(q2.y, r[18], r[19]);
        up2(q2.z, r[20], r[21]); up2(q2.w, r[22], r[23]);
        up2(q3.x, r[24], r[25]);
        r[26] = __uint_as_float(q3.y << 16);
        #pragma unroll
        for (int c = 0; c < 3; ++c){
            const float* rr = r + c * 9;
            const int wi = c * 9 + dy * 3;
            const float w0 = W1c[wi], w1 = W1c[wi+1], w2 = W1c[wi+2];
            #pragma unroll
            for (int xo = 0; xo < 9; ++xo){
                a[xo] = fmaf(rr[xo], w1, a[xo]);
                if (xo >= 1) a[xo] = fmaf(rr[xo-1], w0, a[xo]);
                if (xo <= 7) a[xo] = fmaf(rr[xo+1], w2, a[xo]);
            }
        }
    }
    #pragma unroll
    for (int xo = 0; xo < 9; ++xo){
        float v = a[xo] > 0.f ? a[xo] : 0.f;   // ReLU
        out9[xo] = f2bf(v);
    }
}

__global__ __launch_bounds__(NTHR, 2)
void patch_embed(const float* __restrict__ images,
                 const float* __restrict__ coords,
                 const int*   __restrict__ t_src,
                 const float* __restrict__ W1,
                 const float* __restrict__ b1,
                 const float* __restrict__ W2,
                 const float* __restrict__ b2,
                 float* __restrict__ out)
{
    __shared__ __align__(16) u16 Pf[PP * PATCH_E];   // 22528 B, bf16 patches
    __shared__ __align__(16) u16 Hl[PP * HST];       //  6656 B
    __shared__ __align__(16) u16 W2g[128 * WST];     // 26624 B
    __shared__ int poff[PP];                         // total ~55.9 KB -> 2 blk/CU

    const int tid  = threadIdx.x;
    const int blk  = blockIdx.x;
    const int lane = tid & 63;
    const int w    = tid >> 6;
    const int n16  = lane & 15;
    const int g4   = lane >> 4;
    const int HW   = 384 * 384;

    // per-patch source offsets (round-half-even like jnp.round)
    if (tid < PP) {
        int gp = blk * PP + tid;
        int b = gp >> 11;
        int n = gp & 2047;
        float cx = coords[(size_t)(b * 2048 + n) * 2 + 0];
        float cy = coords[(size_t)(b * 2048 + n) * 2 + 1];
        int u = (int)rintf(cx * 384.0f);
        int v = (int)rintf(cy * 384.0f);
        u = min(max(u, 4), 379);
        v = min(max(v, 4), 379);
        int t = t_src[b * 2048 + n];
        t = min(max(t, 0), 15);
        poff[tid] = ((b * 16 + t) * 3) * HW + (v - 4) * 384 + (u - 4);
    }
    // zero H once (pads [81,104) stay zero forever; [0,81) rewritten per group)
    u32* Hw = (u32*)Hl;
    for (int j = tid; j < PP * (HST / 2); j += NTHR) Hw[j] = 0u;
    __syncthreads();

    // stage patches: [p][y(11, zero-pad rows 0,10)][32 = 3c*9x packed], bf16
    for (int i = tid; i < PP * PATCH_E; i += NTHR) {
        int x32  = i & (PR - 1);
        int rest = i >> 5;          // p*11 + y
        int y = rest % PY;
        int p = rest / PY;
        u16 v = 0;
        if (x32 < 27 && y >= 1 && y <= 9) {
            int c = x32 / 9;
            int x = x32 - c * 9;
            v = f2bf(images[(size_t)poff[p] + c * HW + (y - 1) * 384 + x]);
        }
        Pf[i] = v;
    }

    f32x4 acc[2][2];
    #pragma unroll
    for (int mt = 0; mt < 2; ++mt)
        #pragma unroll
        for (int nt = 0; nt < 2; ++nt) acc[mt][nt] = (f32x4){0.f, 0.f, 0.f, 0.f};

    // conv1 task decomposition: 288 tasks (32 patches x 9 rows)
    const int p0s = tid / 9, y0s = tid - 9 * p0s;
    const int t1 = tid + 256;
    const int p1s = t1 / 9, y1s = t1 - 9 * p1s;     // valid only for tid < 32

    u32* W2gw = (u32*)W2g;

    __syncthreads();   // patches staged

    for (int g = 0; g < 64; ++g) {
        // ---- conv1 for channel g into registers (reads Pf only) ----
        const float* W1c = W1 + g * 27;
        const float bias = b1[g];
        u16 h0[9], h1[9];
        conv1_one(Pf, p0s, y0s, W1c, bias, h0);
        if (tid < 32) conv1_one(Pf, p1s, y1s, W1c, bias, h1);

        __syncthreads();   // all waves done reading Hl/W2g of previous group

        // H writes (byte-granular u16 LDS stores; no cross-thread u32 RMW)
        #pragma unroll
        for (int xo = 0; xo < 9; ++xo) Hl[p0s * HST + y0s * 9 + xo] = h0[xo];
        if (tid < 32) {
            #pragma unroll
            for (int xo = 0; xo < 9; ++xo) Hl[p1s * HST + y1s * 9 + xo] = h1[xo];
        }

        // stage W2[:, g, :] -> W2g[oc][yx] bf16, zeros in [81,104)
        {
            const float* src = W2 + (size_t)g * 81;
            for (int i = tid; i < 128 * (WST / 2); i += NTHR) {
                int oc = i / (WST / 2);
                int pr = i - oc * (WST / 2);
                int yx0 = pr * 2;
                const float* so = src + (size_t)oc * 5184;
                float v0 = (yx0     < 81) ? so[yx0]     : 0.f;
                float v1 = (yx0 + 1 < 81) ? so[yx0 + 1] : 0.f;
                W2gw[i] = (u32)f2bf(v0) | ((u32)f2bf(v1) << 16);
            }
        }

        __syncthreads();   // Hl(g) and W2g(g) ready

        // ---- conv2 partial: 3 MFMA K-steps (K = 96 incl. zero pad) ----
        #pragma unroll
        for (int s = 0; s < 3; ++s) {
            const int ko = s * 32 + g4 * 8;
            bf16x8 a0 = *(const bf16x8*)(Hl + (n16     ) * HST + ko);
            bf16x8 a1 = *(const bf16x8*)(Hl + (16 + n16) * HST + ko);
            bf16x8 b0 = *(const bf16x8*)(W2g + (w * 32 + n16     ) * WST + ko);
            bf16x8 b1 = *(const bf16x8*)(W2g + (w * 32 + 16 + n16) * WST + ko);
            acc[0][0] = __builtin_amdgcn_mfma_f32_16x16x32_bf16(a0, b0, acc[0][0], 0, 0, 0);
            acc[0][1] = __builtin_amdgcn_mfma_f32_16x16x32_bf16(a0, b1, acc[0][1], 0, 0, 0);
            acc[1][0] = __builtin_amdgcn_mfma_f32_16x16x32_bf16(a1, b0, acc[1][0], 0, 0, 0);
            acc[1][1] = __builtin_amdgcn_mfma_f32_16x16x32_bf16(a1, b1, acc[1][1], 0, 0, 0);
        }
    }

    // ---- epilogue: + b2, write fp32 (B,N,128) ----
    const float bias0 = b2[w * 32 + n16];
    const float bias1 = b2[w * 32 + 16 + n16];
    #pragma unroll
    for (int mt = 0; mt < 2; ++mt) {
        #pragma unroll
        for (int r = 0; r < 4; ++r) {
            int p = mt * 16 + g4 * 4 + r;
            size_t rowo = (size_t)(blk * PP + p) * 128;
            out[rowo + w * 32 + n16]      = acc[mt][0][r] + bias0;
            out[rowo + w * 32 + 16 + n16] = acc[mt][1][r] + bias1;
        }
    }
}

extern "C" void kernel_launch(void* const* d_in, const int* in_sizes, int n_in,
                              void* d_out, int out_size, void* d_ws, size_t ws_size,
                              hipStream_t stream)
{
    const float* images = (const float*)d_in[0];
    const float* coords = (const float*)d_in[1];
    const int*   t_src  = (const int*)d_in[2];
    const float* W1     = (const float*)d_in[3];
    const float* b1     = (const float*)d_in[4];
    const float* W2     = (const float*)d_in[5];
    const float* b2     = (const float*)d_in[6];
    float* out = (float*)d_out;

    hipLaunchKernelGGL(patch_embed, dim3(1024), dim3(NTHR), 0, stream,
                       images, coords, t_src, W1, b1, W2, b2, out);
}

// Round 8
// 853.997 us; speedup vs baseline: 1.8732x; 1.8732x over previous
//
#include <hip/hip_runtime.h>
#include <stdint.h>

#define NTHR 256
#define PP   32              // patches per block
#define PR   40              // patch row elems (27 used + pad) -> conflict-free stride
#define PY   11              // rows incl. zero-pad rows y=0, y=10
#define PATCH_E (PY*PR)      // 440 elems per patch
#define HST  104             // H row stride in bf16 elems (52 dw == 20 mod 32)
#define WST  104             // W2g row stride in bf16 elems
#define NCHUNK 11            // uint4 window chunks per thread (128oc*22/256)

typedef __attribute__((ext_vector_type(8))) short bf16x8;
typedef __attribute__((ext_vector_type(4))) float f32x4;
typedef uint32_t u32;
typedef uint16_t u16;

__device__ __forceinline__ u16 f2bf(float f){
    u32 x = __float_as_uint(f);
    return (u16)((x + 0x7fffu + ((x >> 16) & 1u)) >> 16);
}
__device__ __forceinline__ void up2(u32 w, float& lo, float& hi){
    lo = __uint_as_float(w << 16);
    hi = __uint_as_float(w & 0xffff0000u);
}

// ---- conv1, single channel: one task = (patch p, out row yo), 9 outputs ----
__device__ __forceinline__ void conv1_one(const u16* __restrict__ Pf, int p, int yo,
                                          const float* __restrict__ W1c, float bias,
                                          u16* out9)
{
    float a[9];
    #pragma unroll
    for (int x = 0; x < 9; ++x) a[x] = bias;
    const u16* base = Pf + p * PATCH_E + yo * PR;   // padded row index yy+1 = yo+dy
    #pragma unroll
    for (int dy = 0; dy < 3; ++dy){
        const u16* row = base + dy * PR;            // 80 B stride, 16B aligned
        uint4 q0 = *(const uint4*)(row);
        uint4 q1 = *(const uint4*)(row + 8);
        uint4 q2 = *(const uint4*)(row + 16);
        uint2 q3 = *(const uint2*)(row + 24);
        float r[27];
        up2(q0.x, r[0],  r[1]);  up2(q0.y, r[2],  r[3]);
        up2(q0.z, r[4],  r[5]);  up2(q0.w, r[6],  r[7]);
        up2(q1.x, r[8],  r[9]);  up2(q1.y, r[10], r[11]);
        up2(q1.z, r[12], r[13]); up2(q1.w, r[14], r[15]);
        up2(q2.x, r[16], r[17]); up2(q2.y, r[18], r[19]);
        up2(q2.z, r[20], r[21]); up2(q2.w, r[22], r[23]);
        up2(q3.x, r[24], r[25]);
        r[26] = __uint_as_float(q3.y << 16);
        #pragma unroll
        for (int c = 0; c < 3; ++c){
            const float* rr = r + c * 9;
            const int wi = c * 9 + dy * 3;
            const float w0 = W1c[wi], w1 = W1c[wi+1], w2 = W1c[wi+2];
            #pragma unroll
            for (int xo = 0; xo < 9; ++xo){
                a[xo] = fmaf(rr[xo], w1, a[xo]);
                if (xo >= 1) a[xo] = fmaf(rr[xo-1], w0, a[xo]);
                if (xo <= 7) a[xo] = fmaf(rr[xo+1], w2, a[xo]);
            }
        }
    }
    #pragma unroll
    for (int xo = 0; xo < 9; ++xo){
        float v = a[xo] > 0.f ? a[xo] : 0.f;   // ReLU
        out9[xo] = f2bf(v);
    }
}

__global__ __launch_bounds__(NTHR, 2)
void patch_embed(const float* __restrict__ images,
                 const float* __restrict__ coords,
                 const int*   __restrict__ t_src,
                 const float* __restrict__ W1,
                 const float* __restrict__ b1,
                 const float* __restrict__ W2,
                 const float* __restrict__ b2,
                 float* __restrict__ out)
{
    __shared__ __align__(16) u16 Pf[PP * PATCH_E];   // 28160 B, bf16 patches
    __shared__ __align__(16) u16 Hl[PP * HST];       //  6656 B
    __shared__ __align__(16) u16 W2g[128 * WST];     // 26624 B
    __shared__ int poff[PP];                         // total 61568 B -> 2 blk/CU

    const int tid  = threadIdx.x;
    const int blk  = blockIdx.x;
    const int lane = tid & 63;
    const int w    = tid >> 6;
    const int n16  = lane & 15;
    const int g4   = lane >> 4;
    const int HW   = 384 * 384;

    // per-patch source offsets (round-half-even like jnp.round)
    if (tid < PP) {
        int gp = blk * PP + tid;
        int b = gp >> 11;
        int n = gp & 2047;
        float cx = coords[(size_t)(b * 2048 + n) * 2 + 0];
        float cy = coords[(size_t)(b * 2048 + n) * 2 + 1];
        int u = (int)rintf(cx * 384.0f);
        int v = (int)rintf(cy * 384.0f);
        u = min(max(u, 4), 379);
        v = min(max(v, 4), 379);
        int t = t_src[b * 2048 + n];
        t = min(max(t, 0), 15);
        poff[tid] = ((b * 16 + t) * 3) * HW + (v - 4) * 384 + (u - 4);
    }
    // zero Hl and W2g once (pads persist; live regions rewritten per group)
    {
        u32* Hw  = (u32*)Hl;
        u32* Wgw = (u32*)W2g;
        for (int j = tid; j < PP * (HST / 2); j += NTHR)  Hw[j]  = 0u;
        for (int j = tid; j < 128 * (WST / 2); j += NTHR) Wgw[j] = 0u;
    }
    __syncthreads();

    // stage patches: [p][y(11, zero-pad rows 0,10)][40 = 27 used + pad], bf16
    for (int i = tid; i < PP * PATCH_E; i += NTHR) {
        int p    = i / PATCH_E;
        int rem  = i - p * PATCH_E;
        int y    = rem / PR;
        int x40  = rem - y * PR;
        u16 v = 0;
        if (x40 < 27 && y >= 1 && y <= 9) {
            int c = x40 / 9;
            int x = x40 - c * 9;
            v = f2bf(images[(size_t)poff[p] + c * HW + (y - 1) * 384 + x]);
        }
        Pf[i] = v;
    }

    f32x4 acc[2][2];
    #pragma unroll
    for (int mt = 0; mt < 2; ++mt)
        #pragma unroll
        for (int nt = 0; nt < 2; ++nt) acc[mt][nt] = (f32x4){0.f, 0.f, 0.f, 0.f};

    // conv1 task decomposition: 288 tasks (32 patches x 9 rows)
    const int p0s = tid / 9, y0s = tid - 9 * p0s;
    const int t1 = tid + 256;
    const int p1s = t1 / 9, y1s = t1 - 9 * p1s;     // valid only for tid < 32

    // staging-lane constants: flat = tid + j*256 over 128oc x 22 chunks
    const int oc_s = tid / 22;
    const int ch_s = tid - 22 * oc_s;

    // W2 window prefetch for g=0
    uint4 wreg[NCHUNK];
    {
        const int base4 = 0;   // (0*81) & ~3
        int oc = oc_s, ch = ch_s;
        #pragma unroll
        for (int j = 0; j < NCHUNK; ++j) {
            int off = base4 + ch * 4;
            off = off > 5180 ? 5180 : off;
            wreg[j] = *(const uint4*)(W2 + (size_t)oc * 5184 + off);
            oc += 11; ch += 14; if (ch >= 22) { ch -= 22; oc += 1; }  // flat += 256
        }
    }

    __syncthreads();   // patches staged

    for (int g = 0; g < 64; ++g) {
        // ---- conv1 for channel g into registers (reads Pf only) ----
        const float* W1c = W1 + g * 27;
        const float bias = b1[g];
        u16 h0[9], h1[9];
        conv1_one(Pf, p0s, y0s, W1c, bias, h0);
        if (tid < 32) conv1_one(Pf, p1s, y1s, W1c, bias, h1);

        __syncthreads();   // all waves done reading Hl/W2g of previous group

        // H writes
        #pragma unroll
        for (int xo = 0; xo < 9; ++xo) Hl[p0s * HST + y0s * 9 + xo] = h0[xo];
        if (tid < 32) {
            #pragma unroll
            for (int xo = 0; xo < 9; ++xo) Hl[p1s * HST + y1s * 9 + xo] = h1[xo];
        }

        // commit prefetched W2 window (group g) -> W2g[oc][yx], guard yx in [0,81)
        {
            const int d = (g * 81) & 3;
            int oc = oc_s, ch = ch_s;
            #pragma unroll
            for (int j = 0; j < NCHUNK; ++j) {
                int yx0 = ch * 4 - d;
                float f0 = __uint_as_float(wreg[j].x);
                float f1 = __uint_as_float(wreg[j].y);
                float f2 = __uint_as_float(wreg[j].z);
                float f3 = __uint_as_float(wreg[j].w);
                u16* dst = W2g + oc * WST;
                if (yx0 >= 0    && yx0 < 81)     dst[yx0]     = f2bf(f0);
                if (yx0 + 1 >= 0 && yx0 + 1 < 81) dst[yx0 + 1] = f2bf(f1);
                if (yx0 + 2 >= 0 && yx0 + 2 < 81) dst[yx0 + 2] = f2bf(f2);
                if (yx0 + 3 < 81)                 dst[yx0 + 3] = f2bf(f3);
                oc += 11; ch += 14; if (ch >= 22) { ch -= 22; oc += 1; }
            }
        }

        // issue prefetch for group g+1 (hidden under MFMA(g) + conv1(g+1))
        if (g < 63) {
            const int base4 = ((g + 1) * 81) & ~3;
            int oc = oc_s, ch = ch_s;
            #pragma unroll
            for (int j = 0; j < NCHUNK; ++j) {
                int off = base4 + ch * 4;
                off = off > 5180 ? 5180 : off;
                wreg[j] = *(const uint4*)(W2 + (size_t)oc * 5184 + off);
                oc += 11; ch += 14; if (ch >= 22) { ch -= 22; oc += 1; }
            }
        }

        __syncthreads();   // Hl(g) and W2g(g) visible

        // ---- conv2 partial: 3 MFMA K-steps (K = 96 incl. zero pad) ----
        #pragma unroll
        for (int s = 0; s < 3; ++s) {
            const int ko = s * 32 + g4 * 8;
            bf16x8 a0 = *(const bf16x8*)(Hl + (n16     ) * HST + ko);
            bf16x8 a1 = *(const bf16x8*)(Hl + (16 + n16) * HST + ko);
            bf16x8 vb0 = *(const bf16x8*)(W2g + (w * 32 + n16     ) * WST + ko);
            bf16x8 vb1 = *(const bf16x8*)(W2g + (w * 32 + 16 + n16) * WST + ko);
            acc[0][0] = __builtin_amdgcn_mfma_f32_16x16x32_bf16(a0, vb0, acc[0][0], 0, 0, 0);
            acc[0][1] = __builtin_amdgcn_mfma_f32_16x16x32_bf16(a0, vb1, acc[0][1], 0, 0, 0);
            acc[1][0] = __builtin_amdgcn_mfma_f32_16x16x32_bf16(a1, vb0, acc[1][0], 0, 0, 0);
            acc[1][1] = __builtin_amdgcn_mfma_f32_16x16x32_bf16(a1, vb1, acc[1][1], 0, 0, 0);
        }
    }

    // ---- epilogue: + b2, write fp32 (B,N,128) ----
    const float bias0 = b2[w * 32 + n16];
    const float bias1 = b2[w * 32 + 16 + n16];
    #pragma unroll
    for (int mt = 0; mt < 2; ++mt) {
        #pragma unroll
        for (int r = 0; r < 4; ++r) {
            int p = mt * 16 + g4 * 4 + r;
            size_t rowo = (size_t)(blk * PP + p) * 128;
            out[rowo + w * 32 + n16]      = acc[mt][0][r] + bias0;
            out[rowo + w * 32 + 16 + n16] = acc[mt][1][r] + bias1;
        }
    }
}

extern "C" void kernel_launch(void* const* d_in, const int* in_sizes, int n_in,
                              void* d_out, int out_size, void* d_ws, size_t ws_size,
                              hipStream_t stream)
{
    const float* images = (const float*)d_in[0];
    const float* coords = (const float*)d_in[1];
    const int*   t_src  = (const int*)d_in[2];
    const float* W1     = (const float*)d_in[3];
    const float* b1     = (const float*)d_in[4];
    const float* W2     = (const float*)d_in[5];
    const float* b2     = (const float*)d_in[6];
    float* out = (float*)d_out;

    hipLaunchKernelGGL(patch_embed, dim3(1024), dim3(NTHR), 0, stream,
                       images, coords, t_src, W1, b1, W2, b2, out);
}